// Round 8
// baseline (460.574 us; speedup 1.0000x reference)
//
#include <hip/hip_runtime.h>
#include <math.h>
#include <string.h>

#define TSTEPS 40
#define BTOT   16384
#define HDIM   128
#define BT     64            // batch rows per block -> grid 256 = exactly 1 block/CU
#define ZSTR   168           // zbuf row stride in shorts
#define NWAVE  8
#define NRT    4             // row-tiles per wave (BT/16)

typedef __attribute__((ext_vector_type(8))) short bf16x8;
typedef __attribute__((ext_vector_type(4))) float f32x4;
typedef __attribute__((ext_vector_type(4))) unsigned int u32x4;

__device__ __forceinline__ short f2bf(float f) {
    unsigned int u; memcpy(&u, &f, 4);
    u += 0x7fffu + ((u >> 16) & 1u);
    return (short)(u >> 16);
}
__device__ __forceinline__ float bf2f(short s) {
    unsigned int u = ((unsigned int)(unsigned short)s) << 16;
    float f; memcpy(&f, &u, 4);
    return f;
}

// launch_bounds arg2 = min waves/EU: (512,2) -> 8 waves/CU = 1 block -> 256-reg budget.
__global__ __launch_bounds__(512, 2)
void lsnn8(const float* __restrict__ x,
           const float* __restrict__ w_in,
           const float* __restrict__ w_rec,
           const float* __restrict__ w_out,
           const float* __restrict__ dm,
           float* __restrict__ out)
{
    __shared__ short zbuf[2][BT][ZSTR];                 // 43 KB; cols 0..127 z, 128..135 x_t, 136.. = 0
    __shared__ unsigned short maskb[TSTEPS][BT][NWAVE]; // 40 KB spike&keep bitmasks
    // sbuf (40x64x2 f32 = 20 KB) overlays zbuf after the step loop (zbuf dead)
    float* sbuf = (float*)&zbuf[0][0][0];

    const int tid   = threadIdx.x;
    const int l     = tid & 63;
    const int wv    = tid >> 6;
    const int li    = l & 15;
    const int q     = l >> 4;
    const int bbase = blockIdx.x * BT;
    const int hcol  = wv * 16 + li;

    // ---- register-resident B fragments: [w_rec | w_in] 3-way bf16 split ----
    bf16x8 wB[5][3];
    #pragma unroll
    for (int kt = 0; kt < 4; ++kt) {
        const float* src = w_rec + hcol * HDIM + kt * 32 + q * 8;
        #pragma unroll
        for (int i = 0; i < 8; ++i) {
            float w0 = src[i];
            short h0 = f2bf(w0); float r1 = w0 - bf2f(h0);
            short h1 = f2bf(r1); float r2 = r1 - bf2f(h1);
            wB[kt][0][i] = h0; wB[kt][1][i] = h1; wB[kt][2][i] = f2bf(r2);
        }
    }
    #pragma unroll
    for (int i = 0; i < 8; ++i) { wB[4][0][i] = 0; wB[4][1][i] = 0; wB[4][2][i] = 0; }
    if (q == 0) {
        const float* src = w_in + hcol * 8;
        #pragma unroll
        for (int i = 0; i < 8; ++i) {
            float w0 = src[i];
            short h0 = f2bf(w0); float r1 = w0 - bf2f(h0);
            short h1 = f2bf(r1); float r2 = r1 - bf2f(h1);
            wB[4][0][i] = h0; wB[4][1][i] = h1; wB[4][2][i] = f2bf(r2);
        }
    }

    // ---- LSNN state (C-layout: row = rt*16 + q*4 + r, col = hcol) ----
    f32x4 v[NRT], cu[NRT], ba[NRT];
    #pragma unroll
    for (int rt = 0; rt < NRT; ++rt) {
        v[rt]  = (f32x4){0.f,0.f,0.f,0.f};
        cu[rt] = (f32x4){0.f,0.f,0.f,0.f};
        ba[rt] = (f32x4){0.f,0.f,0.f,0.f};
    }

    // ---- encoder: 512 threads = 64 rows x 8 channels ----
    const int er = tid >> 3, ech = tid & 7;
    float ve = 0.f, ce;
    {
        float xv = 50.f * x[(bbase + er) * 4 + (ech & 3)];
        ce = (ech < 4) ? fmaxf(xv, 0.f) : fmaxf(-xv, 0.f);
    }

    const float KA = 1.4285714285714286e-06f;  // DT * (1/700)
    const float KB = 2.5714285714285714e-03f;  // (1/700) * 1.8

    // zero zbuf (both parities; cols >=136 stay 0 during the loop)
    for (int idx = tid; idx < 2 * BT * ZSTR; idx += 512) ((short*)zbuf)[idx] = 0;
    __syncthreads();

    // prologue: x_0 spikes -> zbuf[0]; dm(t=0) -> registers
    {
        float vv = ve + 0.1f * (ce - ve);
        float sp = (vv - 1.0f > 0.f) ? 1.f : 0.f;
        ve = (1.f - sp) * vv;
        zbuf[0][er][128 + ech] = (sp > 0.5f) ? (short)0x3F80 : (short)0;
    }
    float mr[NRT][4];
    {
        const float* dmt = dm + (size_t)bbase * HDIM;
        #pragma unroll
        for (int rt = 0; rt < NRT; ++rt)
            #pragma unroll
            for (int r = 0; r < 4; ++r)
                mr[rt][r] = dmt[(rt * 16 + q * 4 + r) * HDIM + hcol];
    }

    for (int t = 0; t < TSTEPS; ++t) {
        const int p = t & 1;
        __syncthreads();   // zbuf[p] (z_{t-1}, x_t) ready; zbuf[1-p] free

        // 1) dm prefetch for t+1 -> registers (covered by this step's compute)
        float mrn[NRT][4];
        {
            int tn = (t + 1 < TSTEPS) ? t + 1 : TSTEPS - 1;
            const float* dmn = dm + ((size_t)tn * BTOT + bbase) * HDIM;
            #pragma unroll
            for (int rt = 0; rt < NRT; ++rt)
                #pragma unroll
                for (int r = 0; r < 4; ++r)
                    mrn[rt][r] = dmn[(rt * 16 + q * 4 + r) * HDIM + hcol];
        }

        // 2) encoder spike for t+1 -> zbuf[1-p] cols 128..135
        {
            float vv = ve + 0.1f * (ce - ve);
            float sp = (vv - 1.0f > 0.f) ? 1.f : 0.f;
            ve = (1.f - sp) * vv;
            zbuf[1 - p][er][128 + ech] = (sp > 0.5f) ? (short)0x3F80 : (short)0;
        }

        // 3) MFMA: acc[rt] = [z_{t-1} | x_t] @ [w_rec | w_in]^T  (K = 160),
        //    4 independent accumulator chains
        f32x4 acc[NRT];
        #pragma unroll
        for (int rt = 0; rt < NRT; ++rt) {
            f32x4 a = {0.f, 0.f, 0.f, 0.f};
            #pragma unroll
            for (int kt = 0; kt < 5; ++kt) {
                bf16x8 zA = *reinterpret_cast<const bf16x8*>(&zbuf[p][rt * 16 + li][kt * 32 + q * 8]);
                #pragma unroll
                for (int pp = 0; pp < 3; ++pp)
                    a = __builtin_amdgcn_mfma_f32_16x16x32_bf16(zA, wB[kt][pp], a, 0, 0, 0);
            }
            acc[rt] = a;
        }

        // 4) cell update + z publish + spike&keep bitmask (no cross-lane reduce)
        #pragma unroll
        for (int rt = 0; rt < NRT; ++rt) {
            #pragma unroll
            for (int r = 0; r < 4; ++r) {
                const int row = rt * 16 + q * 4 + r;
                float vd = v[rt][r] + 0.1f * (cu[rt][r] - v[rt][r]);
                float id = cu[rt][r] - 0.2f * cu[rt][r];
                float bd = ba[rt][r] + KA * (1.0f - ba[rt][r]);
                float z  = (vd - bd > 0.f) ? 1.f : 0.f;
                v[rt][r]  = (1.f - z) * vd;
                ba[rt][r] = bd + z * KB;
                cu[rt][r] = id + acc[rt][r];
                zbuf[1 - p][row][hcol] = (z > 0.5f) ? (short)0x3F80 : (short)0;
                unsigned long long bm = __ballot((z > 0.5f) && (mr[rt][r] > 1.0f));
                if (li == 0)
                    maskb[t][row][wv] = (unsigned short)(bm >> (q * 16));
            }
        }
        #pragma unroll
        for (int rt = 0; rt < NRT; ++rt)
            #pragma unroll
            for (int r = 0; r < 4; ++r) mr[rt][r] = mrn[rt][r];
    }

    __syncthreads();   // maskb complete; zbuf dead -> reuse as sbuf
    asm volatile("" ::: "memory");

    // ---- batched readout: s[t][row][o] = (z&keep)*2 @ w_out^T via MFMA ----
    bf16x8 woB[4][2];   // B[k][j] = w_out[j][k], cols 0,1 valid; 2-way split
    #pragma unroll
    for (int kt = 0; kt < 4; ++kt) {
        #pragma unroll
        for (int i = 0; i < 8; ++i) {
            float w0 = 0.f;
            if (li < 2) w0 = w_out[li * HDIM + kt * 32 + q * 8 + i];
            short h0 = f2bf(w0);
            woB[kt][0][i] = h0;
            woB[kt][1][i] = f2bf(w0 - bf2f(h0));
        }
    }
    for (int T = wv; T < TSTEPS * NRT; T += NWAVE) {
        const int t  = T >> 2;
        const int rt = T & 3;
        f32x4 ac = {0.f, 0.f, 0.f, 0.f};
        #pragma unroll
        for (int kt = 0; kt < 4; ++kt) {
            unsigned b = (unsigned)maskb[t][rt * 16 + li][2 * kt + (q >> 1)];
            b = (b >> ((q & 1) * 8)) & 0xffu;
            // expand 8 bits -> 8 bf16 values {0, 2.0} (2.0 = 0x4000)
            u32x4 aw;
            aw.x = ((b & 1u)   << 14) | ((b & 2u)   << 29);
            aw.y = ((b & 4u)   << 12) | ((b & 8u)   << 27);
            aw.z = ((b & 16u)  << 10) | ((b & 32u)  << 25);
            aw.w = ((b & 64u)  <<  8) | ((b & 128u) << 23);
            bf16x8 A = __builtin_bit_cast(bf16x8, aw);
            ac = __builtin_amdgcn_mfma_f32_16x16x32_bf16(A, woB[kt][0], ac, 0, 0, 0);
            ac = __builtin_amdgcn_mfma_f32_16x16x32_bf16(A, woB[kt][1], ac, 0, 0, 0);
        }
        if (li < 2) {
            #pragma unroll
            for (int r = 0; r < 4; ++r)
                sbuf[((size_t)t * BT + rt * 16 + q * 4 + r) * 2 + li] = ac[r];
        }
    }
    __syncthreads();   // sbuf complete

    // ---- LI recurrence + max + softmax (waves 0-1: g = (row, o)) ----
    if (wv < 2) {
        const int g = wv * 64 + l;
        const int row = g >> 1, o = g & 1;
        float vo = 0.f, io = 0.f, mx = 0.f;
        for (int t = 0; t < TSTEPS; ++t) {
            float s = sbuf[((size_t)t * BT + row) * 2 + o];
            float von = vo + 0.1f * (io - vo);
            io = io - 0.2f * io + s;
            vo = von;
            mx = fmaxf(mx, vo);
        }
        float other = __shfl_xor(mx, 1);
        float mmax  = fmaxf(mx, other);
        float e  = expf(mx - mmax);
        float eo = expf(other - mmax);
        out[(size_t)(bbase + row) * 2 + o] = e / (e + eo);
    }
}

extern "C" void kernel_launch(void* const* d_in, const int* in_sizes, int n_in,
                              void* d_out, int out_size, void* d_ws, size_t ws_size,
                              hipStream_t stream) {
    const float* x     = (const float*)d_in[0];
    const float* w_in  = (const float*)d_in[1];
    const float* w_rec = (const float*)d_in[2];
    const float* w_out = (const float*)d_in[3];
    const float* dmask = (const float*)d_in[4];
    float* outp = (float*)d_out;

    lsnn8<<<BTOT / BT, 512, 0, stream>>>(x, w_in, w_rec, w_out, dmask, outp);
}